// Round 10
// baseline (146.050 us; speedup 1.0000x reference)
//
#include <hip/hip_runtime.h>
#include <math.h>

// Dims fixed by reference setup_inputs
#define B_ 4
#define S_ 2048
#define D_ 1024
#define G_ 512
#define T_ 2047          // diff rows per batch
#define MTO 32           // output rows per block (grid 256 = 1 block/CU)
#define NR 48            // padded pipeline rows (39 used: 32 outputs + 8-row halo)
#define ABST2 1032       // ABs stride (elems): 2064 B, 16-B aligned
#define VST 520          // Vs stride

typedef __attribute__((ext_vector_type(8))) short short8;
typedef __attribute__((ext_vector_type(4))) short s16x4;
typedef __attribute__((ext_vector_type(4))) float f32x4;

// ws byte offsets
#define WSOFF_RG2 0u                 // 512 f
#define WSOFF_BP1 4096u              // Bpack1 [128][512] short8 (1 MB)
#define WSOFF_BP2 (4096u + 1048576u) // Bpack2 [64][1024] short8 (1 MB)

__device__ inline short to_bf16(float f) {
    union { float f; unsigned u; } v; v.f = f;
    unsigned r = v.u + 0x7fffu + ((v.u >> 16) & 1u);
    return (short)(r >> 16);
}
__device__ inline float fb(unsigned short h) {
    union { unsigned u; float f; } v;
    v.u = ((unsigned)h) << 16;
    return v.f;
}
__device__ inline float fbs(short h) { return fb((unsigned short)h); }
__device__ inline f32x4 MF(short8 a, short8 b, f32x4 c) {
    return __builtin_amdgcn_mfma_f32_16x16x32_bf16(a, b, c, 0, 0, 0);
}

// raw barrier: LDS-visibility only, does NOT drain vmcnt
#define RAWBAR() do {                                            \
    __builtin_amdgcn_sched_barrier(0);                           \
    asm volatile("s_waitcnt lgkmcnt(0)" ::: "memory");           \
    __builtin_amdgcn_s_barrier();                                \
    __builtin_amdgcn_sched_barrier(0);                           \
} while (0)

// ---------------------------------------------------------------------------
// prep (merged):
//  bid<128 : per-wave g = bid*4+wave: rg2[g] = 2/max(||guid[g]||,1e-8);
//            Bpack1[k/8][g][k&7] = bf16(guid[g][k])
//  bid>=128: gg = bid-128: Bpack2[gg][d][j] = bf16(guid[gg*8+j][d])
// ---------------------------------------------------------------------------
__global__ __launch_bounds__(256) void prep_kernel(const float* __restrict__ guid,
                                                   float* __restrict__ rg2,
                                                   short8* __restrict__ Bp1,
                                                   short8* __restrict__ Bp2) {
    int bid = blockIdx.x, tid = threadIdx.x;
    if (bid < 128) {
        int wave = tid >> 6, lane = tid & 63;
        int g = bid * 4 + wave;
        const float4* gp = (const float4*)(guid + (size_t)g * D_);
        float ss = 0.f;
#pragma unroll
        for (int i = 0; i < 4; ++i) {
            float4 v = gp[lane + 64 * i];
            ss += v.x * v.x + v.y * v.y + v.z * v.z + v.w * v.w;
        }
#pragma unroll
        for (int m = 32; m >= 1; m >>= 1) ss += __shfl_xor(ss, m, 64);
        if (lane == 0) rg2[g] = 2.0f / fmaxf(sqrtf(ss), 1e-8f);
#pragma unroll
        for (int h = 0; h < 2; ++h) {
            int kg = lane + 64 * h;
            const float* src = guid + (size_t)g * D_ + kg * 8;
            short8 v;
#pragma unroll
            for (int j = 0; j < 8; ++j) v[j] = to_bf16(src[j]);
            Bp1[(size_t)kg * G_ + g] = v;
        }
    } else {
        int gg = bid - 128;
#pragma unroll
        for (int dd = 0; dd < 4; ++dd) {
            int d = tid + 256 * dd;
            short8 v;
#pragma unroll
            for (int j = 0; j < 8; ++j) v[j] = to_bf16(guid[(size_t)(gg * 8 + j) * D_ + d]);
            Bp2[(size_t)gg * D_ + d] = v;
        }
    }
}

// one gemm1 K-step for k-group ksv using B-ring entry q (3 m-tiles)
#define G1Q3(ksv, q)  {                                                           \
    short8 a0 = *(const short8*)&ABs[l15][(ksv) * 32 + quad * 8];                 \
    short8 a1 = *(const short8*)&ABs[16 + l15][(ksv) * 32 + quad * 8];            \
    short8 a2 = *(const short8*)&ABs[32 + l15][(ksv) * 32 + quad * 8];            \
    acc1[0][0] = MF(a0, q[0], acc1[0][0]); acc1[0][1] = MF(a0, q[1], acc1[0][1]); \
    acc1[1][0] = MF(a1, q[0], acc1[1][0]); acc1[1][1] = MF(a1, q[1], acc1[1][1]); \
    acc1[2][0] = MF(a2, q[0], acc1[2][0]); acc1[2][1] = MF(a2, q[1], acc1[2][1]); }

// ---------------------------------------------------------------------------
// fused_kernel: round-9 structure (verified: fused 51.2 us, no spill) with
// the barrier count cut 7 -> 5:
//  - mrS written by lane 0 in Phase 1 (deletes the post-gemm1 barrier)
//  - cvS section + 2 barriers replaced by per-wave pred row-sums in V-build
// ---------------------------------------------------------------------------
__global__ __launch_bounds__(1024, 4) void fused_kernel(const float* __restrict__ emb,
                                                        const short8* __restrict__ Bp1,
                                                        const short8* __restrict__ Bp2,
                                                        const float* __restrict__ rg2,
                                                        float* __restrict__ out) {
    __shared__ short ABs[NR][ABST2];     // raw diffs full-K; then W (cols<512); then IP [32][ABST2]
    __shared__ short Vs[MTO][VST];       // tap-combined weights (gemm2 A)
    __shared__ float rg2s[G_];
    __shared__ float pred[NR][16];
    __shared__ float magS[NR], rmagS[NR], mrS[NR];
    __shared__ float rwsS[MTO];

    const int tid = threadIdx.x;
    const int wave = tid >> 6, lane = tid & 63;
    const int l15 = lane & 15, quad = lane >> 4;
    // XCD-contiguous swizzle: grid 256 = 8 XCDs x 32. HW round-robins raw
    // blockIdx across XCDs; remap so the 32 blocks on one XCD get contiguous
    // s-tiles (shared 8-row emb halo + shared B-streams stay in that XCD's L2).
    const int bid0 = blockIdx.x;
    const int bid = ((bid0 & 7) << 5) | (bid0 >> 3);   // bijective on [0,256)
    const int b = bid >> 6;
    const int s0 = (bid & 63) << 5;
    const bool edge = (s0 == 0);

    if (tid < G_) rg2s[tid] = rg2[tid];

    // ---- Phase 1: diffs. wave handles rows {w, 16+w, 32+w}; row rr -> t = s0-8+rr ----
#pragma unroll
    for (int ii = 0; ii < 3; ++ii) {
        int rr = wave + 16 * ii;
        int t = s0 - 8 + rr;
        bool valid = (t >= 0) && (rr < 39);
        float ss = 0.f;
        if (valid) {
            const float4* p = (const float4*)(emb + ((size_t)b * S_ + t) * D_);
#pragma unroll
            for (int j = 0; j < 4; ++j) {
                float4 x0 = p[lane + 64 * j];
                float4 x1 = p[lane + 64 * j + 256];
                float4 dv = make_float4(x1.x - x0.x, x1.y - x0.y, x1.z - x0.z, x1.w - x0.w);
                ss += dv.x * dv.x + dv.y * dv.y + dv.z * dv.z + dv.w * dv.w;
                s16x4 h;
                h[0] = to_bf16(dv.x); h[1] = to_bf16(dv.y);
                h[2] = to_bf16(dv.z); h[3] = to_bf16(dv.w);
                *(s16x4*)&ABs[rr][4 * lane + 256 * j] = h;
            }
        } else {
            s16x4 z = (s16x4)0;
#pragma unroll
            for (int j = 0; j < 4; ++j) *(s16x4*)&ABs[rr][4 * lane + 256 * j] = z;
        }
#pragma unroll
        for (int m = 32; m >= 1; m >>= 1) ss += __shfl_xor(ss, m, 64);
        float mag = sqrtf(ss);
        if (lane == 0) {
            float tw = tanhf(2.0f * mag);                        // 0 for invalid
            float rmag = (mag > 1e-6f) ? (1.0f / mag) : 0.0f;
            magS[rr]  = tw;
            rmagS[rr] = rmag;
            mrS[rr]   = 0.6f * tw * rmag;
        }
    }
    RAWBAR();                                            // bar1

    // ---- Phase 2: gemm1 [48 x 512], K=1024, 4-deep B ring. wave owns g [32w,32w+32) ----
    f32x4 acc1[3][2];
#pragma unroll
    for (int mt = 0; mt < 3; ++mt)
#pragma unroll
        for (int nt = 0; nt < 2; ++nt) acc1[mt][nt] = (f32x4)0.f;
    {
        const short8* Bb = Bp1 + (size_t)quad * G_ + wave * 32 + l15;
        short8 q0[2], q1[2], q2[2], q3[2];
        q0[0] = Bb[0];          q0[1] = Bb[16];
        q1[0] = Bb[4 * G_];     q1[1] = Bb[4 * G_ + 16];
        q2[0] = Bb[8 * G_];     q2[1] = Bb[8 * G_ + 16];
        q3[0] = Bb[12 * G_];    q3[1] = Bb[12 * G_ + 16];

        // rwsS while the ring loads fly (wave 0's first 32 lanes only)
        if (tid < MTO) {
            int w = edge ? ((tid < 8) ? tid : 8) : 8;
            float rw = (w > 1) ? 0.9f / (float)(w - 1) : 0.f;
            float s = 0.f;
#pragma unroll
            for (int a = 1; a <= 8; ++a) {
                float lin = (a <= w) ? ((w > 1) ? (0.1f + rw * (float)(w - a)) : 0.1f) : 0.f;
                s += lin * magS[tid + 8 - a];
            }
            rwsS[tid] = 1.0f / fmaxf(s, 1e-8f);
        }

#pragma unroll
        for (int k4 = 0; k4 < 32; k4 += 4) {
            G1Q3(k4 + 0, q0); if (k4 < 28) { q0[0] = Bb[(size_t)(k4 + 4) * 4 * G_]; q0[1] = Bb[(size_t)(k4 + 4) * 4 * G_ + 16]; }
            G1Q3(k4 + 1, q1); if (k4 < 28) { q1[0] = Bb[(size_t)(k4 + 5) * 4 * G_]; q1[1] = Bb[(size_t)(k4 + 5) * 4 * G_ + 16]; }
            G1Q3(k4 + 2, q2); if (k4 < 28) { q2[0] = Bb[(size_t)(k4 + 6) * 4 * G_]; q2[1] = Bb[(size_t)(k4 + 6) * 4 * G_ + 16]; }
            G1Q3(k4 + 3, q3); if (k4 < 28) { q3[0] = Bb[(size_t)(k4 + 7) * 4 * G_]; q3[1] = Bb[(size_t)(k4 + 7) * 4 * G_ + 16]; }
        }
    }
    // no barrier here: FIR reads only bar1-protected LDS (ABs, mrS)

    // ---- Phase 3: normed-part 8-tap FIR over raw diffs. lane owns column d = tid ----
    float np_[MTO];
    {
        float pr[8];
#pragma unroll
        for (int r = 0; r < 8; ++r) pr[r] = mrS[r] * fbs(ABs[r][tid]);
        if (!edge) {
#pragma unroll
            for (int i = 0; i < MTO; ++i) {
                float s = 0.f;
#pragma unroll
                for (int a = 1; a <= 8; ++a)
                    s += (0.1f + (0.9f / 7.f) * (float)(8 - a)) * pr[(i + 8 - a) & 7];
                np_[i] = s;
                if (i < 31) pr[i & 7] = mrS[i + 8] * fbs(ABs[i + 8][tid]);
            }
        } else {
#pragma unroll
            for (int i = 0; i < MTO; ++i) {
                int w = (i < 8) ? i : 8;
                float rw = (w > 1) ? 0.9f / (float)(w - 1) : 0.f;
                float s = 0.f;
#pragma unroll
                for (int a = 1; a <= 8; ++a) {
                    float lin = (a <= w) ? ((w > 1) ? (0.1f + rw * (float)(w - a)) : 0.1f) : 0.f;
                    s += lin * pr[(i + 8 - a) & 7];
                }
                np_[i] = s;
                if (i < 31) pr[i & 7] = mrS[i + 8] * fbs(ABs[i + 8][tid]);
            }
        }
    }

    // ---- Phase 4: softmax (no max-sub; logits in [-2,2]); unnormalized exp ----
    float psum[3][4];
#pragma unroll
    for (int mt = 0; mt < 3; ++mt)
#pragma unroll
        for (int r2 = 0; r2 < 4; ++r2) psum[mt][r2] = 0.f;
    {
        float rmv[3][4];
#pragma unroll
        for (int mt = 0; mt < 3; ++mt)
#pragma unroll
            for (int r2 = 0; r2 < 4; ++r2) rmv[mt][r2] = rmagS[mt * 16 + quad * 4 + r2];
#pragma unroll
        for (int mt = 0; mt < 3; ++mt)
#pragma unroll
            for (int nt = 0; nt < 2; ++nt) {
                float rgv = rg2s[wave * 32 + nt * 16 + l15];
#pragma unroll
                for (int r2 = 0; r2 < 4; ++r2) {
                    float e = __expf(acc1[mt][nt][r2] * rgv * rmv[mt][r2]);
                    acc1[mt][nt][r2] = e;
                    psum[mt][r2] += e;
                }
            }
#pragma unroll
        for (int m = 8; m >= 1; m >>= 1)
#pragma unroll
            for (int mt = 0; mt < 3; ++mt)
#pragma unroll
                for (int r2 = 0; r2 < 4; ++r2)
                    psum[mt][r2] += __shfl_xor(psum[mt][r2], m, 16);
    }
    RAWBAR();                    // bar2: all FIR/gemm1 reads of ABs done -> safe to overwrite

    // W (exp) -> ABs cols 0..511; partial sums -> pred
#pragma unroll
    for (int mt = 0; mt < 3; ++mt)
#pragma unroll
        for (int nt = 0; nt < 2; ++nt)
#pragma unroll
            for (int r2 = 0; r2 < 4; ++r2)
                ABs[mt * 16 + quad * 4 + r2][wave * 32 + nt * 16 + l15] =
                    to_bf16(acc1[mt][nt][r2]);
    if (l15 == 0) {
#pragma unroll
        for (int mt = 0; mt < 3; ++mt)
#pragma unroll
            for (int r2 = 0; r2 < 4; ++r2)
                pred[mt * 16 + quad * 4 + r2][wave] = psum[mt][r2];
    }
    RAWBAR();                    // bar3: W + pred visible

    // ---- Phase 5: V-build. wave owns rows i = 2w, 2w+1; per-wave pred row sums ----
    {
        float sums[9];
#pragma unroll
        for (int r = 0; r < 9; ++r) {
            int rr = 2 * wave + r;
            float s = 0.f;
#pragma unroll
            for (int w2 = 0; w2 < 16; ++w2) s += pred[rr][w2];
            sums[r] = s;
        }
#pragma unroll
        for (int ii = 0; ii < 2; ++ii) {
            int i = wave * 2 + ii;
            int w = edge ? ((i < 8) ? i : 8) : 8;
            float rw = (w > 1) ? 0.9f / (float)(w - 1) : 0.f;
            float c[8];
#pragma unroll
            for (int a = 1; a <= 8; ++a) {
                int rr = i + 8 - a;
                float lin = (a <= w) ? ((w > 1) ? (0.1f + rw * (float)(w - a)) : 0.1f) : 0.f;
                c[a - 1] = lin * 0.4f * magS[rr] / sums[rr - 2 * wave];
            }
            float v[8];
#pragma unroll
            for (int j = 0; j < 8; ++j) v[j] = 0.f;
#pragma unroll
            for (int a = 1; a <= 8; ++a) {
                short8 e = *(const short8*)&ABs[i + 8 - a][lane * 8];
#pragma unroll
                for (int j = 0; j < 8; ++j) v[j] += c[a - 1] * fbs(e[j]);
            }
            short8 vo;
#pragma unroll
            for (int j = 0; j < 8; ++j) vo[j] = to_bf16(v[j]);
            *(short8*)&Vs[i][lane * 8] = vo;
        }
    }
    RAWBAR();                    // bar4: Vs visible

    // ---- Phase 6: gemm2 [32 x 1024], K=512, two 32-d halves; IP -> ABs (bf16) ----
    short* IPb = &ABs[0][0];
#pragma unroll
    for (int half = 0; half < 2; ++half) {
        f32x4 acc2[2][2];
#pragma unroll
        for (int mt = 0; mt < 2; ++mt)
#pragma unroll
            for (int nt = 0; nt < 2; ++nt) acc2[mt][nt] = (f32x4)0.f;
        const short8* Bb2 = Bp2 + (size_t)quad * D_ + wave * 64 + half * 32 + l15;
        short8 bc0 = Bb2[0], bc1 = Bb2[16], bn0, bn1;
#pragma unroll
        for (int ks = 0; ks < 16; ++ks) {
            if (ks < 15) {
                const short8* Bx = Bb2 + (size_t)(ks + 1) * 4 * D_;
                bn0 = Bx[0]; bn1 = Bx[16];
            }
            short8 a0 = *(const short8*)&Vs[l15][ks * 32 + quad * 8];
            short8 a1 = *(const short8*)&Vs[16 + l15][ks * 32 + quad * 8];
            acc2[0][0] = MF(a0, bc0, acc2[0][0]); acc2[0][1] = MF(a0, bc1, acc2[0][1]);
            acc2[1][0] = MF(a1, bc0, acc2[1][0]); acc2[1][1] = MF(a1, bc1, acc2[1][1]);
            bc0 = bn0; bc1 = bn1;
        }
#pragma unroll
        for (int mt = 0; mt < 2; ++mt)
#pragma unroll
            for (int ntl = 0; ntl < 2; ++ntl) {
                int d2 = wave * 64 + half * 32 + ntl * 16 + l15;
#pragma unroll
                for (int r2 = 0; r2 < 4; ++r2)
                    IPb[(size_t)(mt * 16 + quad * 4 + r2) * ABST2 + d2] =
                        to_bf16(acc2[mt][ntl][r2]);
            }
    }
    RAWBAR();                    // bar5: IP visible

    // ---- Phase 7: out = (NP + IP) * rws. lane owns column d = tid ----
    {
        float* ob = out + ((size_t)b * S_ + s0) * D_ + tid;
#pragma unroll
        for (int i = 0; i < MTO; ++i) {
            float ip = fbs(IPb[(size_t)i * ABST2 + tid]);
            ob[(size_t)i * D_] = (np_[i] + ip) * rwsS[i];
        }
    }
}

// ---------------------------------------------------------------------------
extern "C" void kernel_launch(void* const* d_in, const int* in_sizes, int n_in,
                              void* d_out, int out_size, void* d_ws, size_t ws_size,
                              hipStream_t stream) {
    const float* emb  = (const float*)d_in[0];
    const float* guid = (const float*)d_in[1];
    float* out = (float*)d_out;
    char* ws = (char*)d_ws;

    float*  rg2 = (float*)(ws + WSOFF_RG2);
    short8* Bp1 = (short8*)(ws + WSOFF_BP1);
    short8* Bp2 = (short8*)(ws + WSOFF_BP2);

    prep_kernel<<<192, 256, 0, stream>>>(guid, rg2, Bp1, Bp2);
    fused_kernel<<<256, 1024, 0, stream>>>(emb, Bp1, Bp2, rg2, out);
}

// Round 11
// 120.074 us; speedup vs baseline: 1.2163x; 1.2163x over previous
//
#include <hip/hip_runtime.h>
#include <math.h>

// Dims fixed by reference setup_inputs
#define B_ 4
#define S_ 2048
#define D_ 1024
#define G_ 512
#define T_ 2047          // diff rows per batch
#define MTO 32           // output rows per block (grid 256 = 1 block/CU)
#define NR 48            // padded pipeline rows (39 used: 32 outputs + 8-row halo)
#define ABST2 1032       // ABs stride (elems): 2064 B, 16-B aligned
#define VST 520          // Vs stride

typedef __attribute__((ext_vector_type(8))) short short8;
typedef __attribute__((ext_vector_type(4))) short s16x4;
typedef __attribute__((ext_vector_type(4))) float f32x4;

// ws byte offsets
#define WSOFF_RG2 0u                 // 512 f
#define WSOFF_BP1 4096u              // Bpack1 [128][512] short8 (1 MB)
#define WSOFF_BP2 (4096u + 1048576u) // Bpack2 [64][1024] short8 (1 MB)

__device__ inline short to_bf16(float f) {
    union { float f; unsigned u; } v; v.f = f;
    unsigned r = v.u + 0x7fffu + ((v.u >> 16) & 1u);
    return (short)(r >> 16);
}
__device__ inline float fb(unsigned short h) {
    union { unsigned u; float f; } v;
    v.u = ((unsigned)h) << 16;
    return v.f;
}
__device__ inline float fbs(short h) { return fb((unsigned short)h); }
__device__ inline f32x4 MF(short8 a, short8 b, f32x4 c) {
    return __builtin_amdgcn_mfma_f32_16x16x32_bf16(a, b, c, 0, 0, 0);
}

// raw barrier: LDS-visibility only, does NOT drain vmcnt
#define RAWBAR() do {                                            \
    __builtin_amdgcn_sched_barrier(0);                           \
    asm volatile("s_waitcnt lgkmcnt(0)" ::: "memory");           \
    __builtin_amdgcn_s_barrier();                                \
    __builtin_amdgcn_sched_barrier(0);                           \
} while (0)

// ---------------------------------------------------------------------------
// prep (merged):
//  bid<128 : per-wave g = bid*4+wave: rg2[g] = 2/max(||guid[g]||,1e-8);
//            Bpack1[k/8][g][k&7] = bf16(guid[g][k])
//  bid>=128: gg = bid-128: Bpack2[gg][d][j] = bf16(guid[gg*8+j][d])
// ---------------------------------------------------------------------------
__global__ __launch_bounds__(256) void prep_kernel(const float* __restrict__ guid,
                                                   float* __restrict__ rg2,
                                                   short8* __restrict__ Bp1,
                                                   short8* __restrict__ Bp2) {
    int bid = blockIdx.x, tid = threadIdx.x;
    if (bid < 128) {
        int wave = tid >> 6, lane = tid & 63;
        int g = bid * 4 + wave;
        const float4* gp = (const float4*)(guid + (size_t)g * D_);
        float ss = 0.f;
#pragma unroll
        for (int i = 0; i < 4; ++i) {
            float4 v = gp[lane + 64 * i];
            ss += v.x * v.x + v.y * v.y + v.z * v.z + v.w * v.w;
        }
#pragma unroll
        for (int m = 32; m >= 1; m >>= 1) ss += __shfl_xor(ss, m, 64);
        if (lane == 0) rg2[g] = 2.0f / fmaxf(sqrtf(ss), 1e-8f);
#pragma unroll
        for (int h = 0; h < 2; ++h) {
            int kg = lane + 64 * h;
            const float* src = guid + (size_t)g * D_ + kg * 8;
            short8 v;
#pragma unroll
            for (int j = 0; j < 8; ++j) v[j] = to_bf16(src[j]);
            Bp1[(size_t)kg * G_ + g] = v;
        }
    } else {
        int gg = bid - 128;
#pragma unroll
        for (int dd = 0; dd < 4; ++dd) {
            int d = tid + 256 * dd;
            short8 v;
#pragma unroll
            for (int j = 0; j < 8; ++j) v[j] = to_bf16(guid[(size_t)(gg * 8 + j) * D_ + d]);
            Bp2[(size_t)gg * D_ + d] = v;
        }
    }
}

// one gemm1 K-step for k-group ksv using B-ring entry q (3 m-tiles)
#define G1Q3(ksv, q)  {                                                           \
    short8 a0 = *(const short8*)&ABs[l15][(ksv) * 32 + quad * 8];                 \
    short8 a1 = *(const short8*)&ABs[16 + l15][(ksv) * 32 + quad * 8];            \
    short8 a2 = *(const short8*)&ABs[32 + l15][(ksv) * 32 + quad * 8];            \
    acc1[0][0] = MF(a0, q[0], acc1[0][0]); acc1[0][1] = MF(a0, q[1], acc1[0][1]); \
    acc1[1][0] = MF(a1, q[0], acc1[1][0]); acc1[1][1] = MF(a1, q[1], acc1[1][1]); \
    acc1[2][0] = MF(a2, q[0], acc1[2][0]); acc1[2][1] = MF(a2, q[1], acc1[2][1]); }

// ---------------------------------------------------------------------------
// fused_kernel: round-4 structure (verified no-spill) + XCD-contiguous block
// swizzle. Block = (b, s0): 32 output rows. 39 diff rows (halo recompute),
// gemm1 [48x512] K=1024 bf16, softmax, tap-combined weights V [32x512],
// gemm2 V*guid, in-LDS 8-tap FIR for the normed part, final f32 out.
// NOTE: V-build MUST use the cvS-in-LDS variant; the per-wave sums[9]
// register variant crosses the 64-VGPR cliff and spills ~400 B/thread
// (rounds 5-8, 10: +104 MB WRITE, +29 us).
// ---------------------------------------------------------------------------
__global__ __launch_bounds__(1024, 4) void fused_kernel(const float* __restrict__ emb,
                                                        const short8* __restrict__ Bp1,
                                                        const short8* __restrict__ Bp2,
                                                        const float* __restrict__ rg2,
                                                        float* __restrict__ out) {
    __shared__ short ABs[NR][ABST2];     // raw diffs full-K; then W (cols<512); then IP [32][ABST2]
    __shared__ short Vs[MTO][VST];       // tap-combined weights (gemm2 A)
    __shared__ float rg2s[G_];
    __shared__ float pred[NR][16];
    __shared__ float magS[NR], rmagS[NR], mrS[NR], cvS[NR];
    __shared__ float rwsS[MTO];

    const int tid = threadIdx.x;
    const int wave = tid >> 6, lane = tid & 63;
    const int l15 = lane & 15, quad = lane >> 4;
    // XCD-contiguous swizzle: grid 256 = 8 XCDs x 32. HW round-robins raw
    // blockIdx across XCDs; remap so the 32 blocks on one XCD get contiguous
    // s-tiles (shared 8-row emb halo + shared B-streams stay in that XCD's L2).
    const int bid0 = blockIdx.x;
    const int bid = ((bid0 & 7) << 5) | (bid0 >> 3);   // bijective on [0,256)
    const int b = bid >> 6;
    const int s0 = (bid & 63) << 5;
    const bool edge = (s0 == 0);

    if (tid < G_) rg2s[tid] = rg2[tid];

    // ---- Phase 1: diffs. wave handles rows {w, 16+w, 32+w}; row rr -> t = s0-8+rr ----
#pragma unroll
    for (int ii = 0; ii < 3; ++ii) {
        int rr = wave + 16 * ii;
        int t = s0 - 8 + rr;
        bool valid = (t >= 0) && (rr < 39);
        float ss = 0.f;
        if (valid) {
            const float4* p = (const float4*)(emb + ((size_t)b * S_ + t) * D_);
#pragma unroll
            for (int j = 0; j < 4; ++j) {
                float4 x0 = p[lane + 64 * j];
                float4 x1 = p[lane + 64 * j + 256];
                float4 dv = make_float4(x1.x - x0.x, x1.y - x0.y, x1.z - x0.z, x1.w - x0.w);
                ss += dv.x * dv.x + dv.y * dv.y + dv.z * dv.z + dv.w * dv.w;
                s16x4 h;
                h[0] = to_bf16(dv.x); h[1] = to_bf16(dv.y);
                h[2] = to_bf16(dv.z); h[3] = to_bf16(dv.w);
                *(s16x4*)&ABs[rr][4 * lane + 256 * j] = h;
            }
        } else {
            s16x4 z = (s16x4)0;
#pragma unroll
            for (int j = 0; j < 4; ++j) *(s16x4*)&ABs[rr][4 * lane + 256 * j] = z;
        }
#pragma unroll
        for (int m = 32; m >= 1; m >>= 1) ss += __shfl_xor(ss, m, 64);
        float mag = sqrtf(ss);
        if (lane == 0) {
            magS[rr]  = tanhf(2.0f * mag);                       // 0 for invalid
            rmagS[rr] = (mag > 1e-6f) ? (1.0f / mag) : 0.0f;
        }
    }
    RAWBAR();

    // helpers needing only magS/rmagS (visible to all after next bar)
    if (tid < NR) mrS[tid] = 0.6f * magS[tid] * rmagS[tid];
    if (tid < MTO) {
        int w = edge ? ((tid < 8) ? tid : 8) : 8;
        float rw = (w > 1) ? 0.9f / (float)(w - 1) : 0.f;
        float s = 0.f;
#pragma unroll
        for (int a = 1; a <= 8; ++a) {
            float lin = (a <= w) ? ((w > 1) ? (0.1f + rw * (float)(w - a)) : 0.1f) : 0.f;
            s += lin * magS[tid + 8 - a];
        }
        rwsS[tid] = 1.0f / fmaxf(s, 1e-8f);
    }

    // ---- Phase 2: gemm1 [48 x 512], K=1024, 4-deep B ring. wave owns g [32w,32w+32) ----
    f32x4 acc1[3][2];
#pragma unroll
    for (int mt = 0; mt < 3; ++mt)
#pragma unroll
        for (int nt = 0; nt < 2; ++nt) acc1[mt][nt] = (f32x4)0.f;
    {
        const short8* Bb = Bp1 + (size_t)quad * G_ + wave * 32 + l15;
        short8 q0[2], q1[2], q2[2], q3[2];
        q0[0] = Bb[0];          q0[1] = Bb[16];
        q1[0] = Bb[4 * G_];     q1[1] = Bb[4 * G_ + 16];
        q2[0] = Bb[8 * G_];     q2[1] = Bb[8 * G_ + 16];
        q3[0] = Bb[12 * G_];    q3[1] = Bb[12 * G_ + 16];
#pragma unroll
        for (int k4 = 0; k4 < 32; k4 += 4) {
            G1Q3(k4 + 0, q0); if (k4 < 28) { q0[0] = Bb[(size_t)(k4 + 4) * 4 * G_]; q0[1] = Bb[(size_t)(k4 + 4) * 4 * G_ + 16]; }
            G1Q3(k4 + 1, q1); if (k4 < 28) { q1[0] = Bb[(size_t)(k4 + 5) * 4 * G_]; q1[1] = Bb[(size_t)(k4 + 5) * 4 * G_ + 16]; }
            G1Q3(k4 + 2, q2); if (k4 < 28) { q2[0] = Bb[(size_t)(k4 + 6) * 4 * G_]; q2[1] = Bb[(size_t)(k4 + 6) * 4 * G_ + 16]; }
            G1Q3(k4 + 3, q3); if (k4 < 28) { q3[0] = Bb[(size_t)(k4 + 7) * 4 * G_]; q3[1] = Bb[(size_t)(k4 + 7) * 4 * G_ + 16]; }
        }
    }
    RAWBAR();                    // mrS/rwsS visible

    // ---- Phase 3: normed-part 8-tap FIR over raw diffs. lane owns column d = tid ----
    float np_[MTO];
    {
        float pr[8];
#pragma unroll
        for (int r = 0; r < 8; ++r) pr[r] = mrS[r] * fbs(ABs[r][tid]);
        if (!edge) {
#pragma unroll
            for (int i = 0; i < MTO; ++i) {
                float s = 0.f;
#pragma unroll
                for (int a = 1; a <= 8; ++a)
                    s += (0.1f + (0.9f / 7.f) * (float)(8 - a)) * pr[(i + 8 - a) & 7];
                np_[i] = s;
                if (i < 31) pr[i & 7] = mrS[i + 8] * fbs(ABs[i + 8][tid]);
            }
        } else {
#pragma unroll
            for (int i = 0; i < MTO; ++i) {
                int w = (i < 8) ? i : 8;
                float rw = (w > 1) ? 0.9f / (float)(w - 1) : 0.f;
                float s = 0.f;
#pragma unroll
                for (int a = 1; a <= 8; ++a) {
                    float lin = (a <= w) ? ((w > 1) ? (0.1f + rw * (float)(w - a)) : 0.1f) : 0.f;
                    s += lin * pr[(i + 8 - a) & 7];
                }
                np_[i] = s;
                if (i < 31) pr[i & 7] = mrS[i + 8] * fbs(ABs[i + 8][tid]);
            }
        }
    }

    // ---- Phase 4: softmax (no max-sub; logits in [-2,2]); unnormalized exp ----
    float psum[3][4];
#pragma unroll
    for (int mt = 0; mt < 3; ++mt)
#pragma unroll
        for (int r2 = 0; r2 < 4; ++r2) psum[mt][r2] = 0.f;
    {
        float rmv[3][4];
#pragma unroll
        for (int mt = 0; mt < 3; ++mt)
#pragma unroll
            for (int r2 = 0; r2 < 4; ++r2) rmv[mt][r2] = rmagS[mt * 16 + quad * 4 + r2];
#pragma unroll
        for (int mt = 0; mt < 3; ++mt)
#pragma unroll
            for (int nt = 0; nt < 2; ++nt) {
                float rgv = rg2s[wave * 32 + nt * 16 + l15];
#pragma unroll
                for (int r2 = 0; r2 < 4; ++r2) {
                    float e = __expf(acc1[mt][nt][r2] * rgv * rmv[mt][r2]);
                    acc1[mt][nt][r2] = e;
                    psum[mt][r2] += e;
                }
            }
#pragma unroll
        for (int m = 8; m >= 1; m >>= 1)
#pragma unroll
            for (int mt = 0; mt < 3; ++mt)
#pragma unroll
                for (int r2 = 0; r2 < 4; ++r2)
                    psum[mt][r2] += __shfl_xor(psum[mt][r2], m, 16);
    }
    RAWBAR();                    // all FIR/gemm1 reads of ABs done -> safe to overwrite
    // W (exp) -> ABs cols 0..511; partial sums -> pred
#pragma unroll
    for (int mt = 0; mt < 3; ++mt)
#pragma unroll
        for (int nt = 0; nt < 2; ++nt)
#pragma unroll
            for (int r2 = 0; r2 < 4; ++r2)
                ABs[mt * 16 + quad * 4 + r2][wave * 32 + nt * 16 + l15] =
                    to_bf16(acc1[mt][nt][r2]);
    if (l15 == 0) {
#pragma unroll
        for (int mt = 0; mt < 3; ++mt)
#pragma unroll
            for (int r2 = 0; r2 < 4; ++r2)
                pred[mt * 16 + quad * 4 + r2][wave] = psum[mt][r2];
    }
    RAWBAR();
    if (tid < NR) {
        float s = 0.f;
#pragma unroll
        for (int w2 = 0; w2 < 16; ++w2) s += pred[tid][w2];
        cvS[tid] = 0.4f * magS[tid] / s;     // folds magw, 0.4, 1/sumexp
    }
    RAWBAR();

    // ---- Phase 5: V-build: V[i][g] = sum_a lin*cvS[i+8-a] * W[i+8-a][g]. wave: i=2w,2w+1 ----
#pragma unroll
    for (int ii = 0; ii < 2; ++ii) {
        int i = wave * 2 + ii;
        int w = edge ? ((i < 8) ? i : 8) : 8;
        float rw = (w > 1) ? 0.9f / (float)(w - 1) : 0.f;
        float c[8];
#pragma unroll
        for (int a = 1; a <= 8; ++a) {
            float lin = (a <= w) ? ((w > 1) ? (0.1f + rw * (float)(w - a)) : 0.1f) : 0.f;
            c[a - 1] = lin * cvS[i + 8 - a];
        }
        float v[8];
#pragma unroll
        for (int j = 0; j < 8; ++j) v[j] = 0.f;
#pragma unroll
        for (int a = 1; a <= 8; ++a) {
            short8 e = *(const short8*)&ABs[i + 8 - a][lane * 8];
#pragma unroll
            for (int j = 0; j < 8; ++j) v[j] += c[a - 1] * fbs(e[j]);
        }
        short8 vo;
#pragma unroll
        for (int j = 0; j < 8; ++j) vo[j] = to_bf16(v[j]);
        *(short8*)&Vs[i][lane * 8] = vo;
    }
    RAWBAR();

    // ---- Phase 6: gemm2 [32 x 1024], K=512, two 32-d halves; IP -> ABs (bf16) ----
    short* IPb = &ABs[0][0];
#pragma unroll
    for (int half = 0; half < 2; ++half) {
        f32x4 acc2[2][2];
#pragma unroll
        for (int mt = 0; mt < 2; ++mt)
#pragma unroll
            for (int nt = 0; nt < 2; ++nt) acc2[mt][nt] = (f32x4)0.f;
        const short8* Bb2 = Bp2 + (size_t)quad * D_ + wave * 64 + half * 32 + l15;
        short8 bc0 = Bb2[0], bc1 = Bb2[16], bn0, bn1;
#pragma unroll
        for (int ks = 0; ks < 16; ++ks) {
            if (ks < 15) {
                const short8* Bx = Bb2 + (size_t)(ks + 1) * 4 * D_;
                bn0 = Bx[0]; bn1 = Bx[16];
            }
            short8 a0 = *(const short8*)&Vs[l15][ks * 32 + quad * 8];
            short8 a1 = *(const short8*)&Vs[16 + l15][ks * 32 + quad * 8];
            acc2[0][0] = MF(a0, bc0, acc2[0][0]); acc2[0][1] = MF(a0, bc1, acc2[0][1]);
            acc2[1][0] = MF(a1, bc0, acc2[1][0]); acc2[1][1] = MF(a1, bc1, acc2[1][1]);
            bc0 = bn0; bc1 = bn1;
        }
#pragma unroll
        for (int mt = 0; mt < 2; ++mt)
#pragma unroll
            for (int ntl = 0; ntl < 2; ++ntl) {
                int d2 = wave * 64 + half * 32 + ntl * 16 + l15;
#pragma unroll
                for (int r2 = 0; r2 < 4; ++r2)
                    IPb[(size_t)(mt * 16 + quad * 4 + r2) * ABST2 + d2] =
                        to_bf16(acc2[mt][ntl][r2]);
            }
    }
    RAWBAR();

    // ---- Phase 7: out = (NP + IP) / wsum. lane owns column d = tid ----
    {
        float* ob = out + ((size_t)b * S_ + s0) * D_ + tid;
#pragma unroll
        for (int i = 0; i < MTO; ++i) {
            float ip = fbs(IPb[(size_t)i * ABST2 + tid]);
            ob[(size_t)i * D_] = (np_[i] + ip) * rwsS[i];
        }
    }
}

// ---------------------------------------------------------------------------
extern "C" void kernel_launch(void* const* d_in, const int* in_sizes, int n_in,
                              void* d_out, int out_size, void* d_ws, size_t ws_size,
                              hipStream_t stream) {
    const float* emb  = (const float*)d_in[0];
    const float* guid = (const float*)d_in[1];
    float* out = (float*)d_out;
    char* ws = (char*)d_ws;

    float*  rg2 = (float*)(ws + WSOFF_RG2);
    short8* Bp1 = (short8*)(ws + WSOFF_BP1);
    short8* Bp2 = (short8*)(ws + WSOFF_BP2);

    prep_kernel<<<192, 256, 0, stream>>>(guid, rg2, Bp1, Bp2);
    fused_kernel<<<256, 1024, 0, stream>>>(emb, Bp1, Bp2, rg2, out);
}

// Round 12
// 115.090 us; speedup vs baseline: 1.2690x; 1.0433x over previous
//
#include <hip/hip_runtime.h>
#include <math.h>

// Dims fixed by reference setup_inputs
#define B_ 4
#define S_ 2048
#define D_ 1024
#define G_ 512
#define MTO 32           // output rows per block (grid 256 = 1 block/CU)
#define NR 48            // padded pipeline rows (39 used: 32 outputs + 8-row halo)
// region A: bf16 diffs [39][DHST] -> W [48][WST] -> IP [32][IPST]
#define DHST 1032        // shorts
#define WST 520
#define IPST 1032
// region B: i8 diffs [48][D8ST] -> V [32][VST]
#define D8ST 1040        // bytes
#define VST 520          // shorts

typedef __attribute__((ext_vector_type(8))) short short8;
typedef __attribute__((ext_vector_type(4))) short s16x4;
typedef __attribute__((ext_vector_type(4))) float f32x4;
typedef __attribute__((ext_vector_type(4))) int i32x4;

// ws byte offsets
#define WSOFF_RG2 0u                 // 512 f (per-g folded scale)
#define WSOFF_BP1 4096u              // i8 Bpack1 [64][512] x 16B = 512 KB
#define WSOFF_BP2 528384u            // bf16 Bpack2 [64][1024] short8 = 1 MB

__device__ inline short to_bf16(float f) {
    union { float f; unsigned u; } v; v.f = f;
    unsigned r = v.u + 0x7fffu + ((v.u >> 16) & 1u);
    return (short)(r >> 16);
}
__device__ inline float fb(unsigned short h) {
    union { unsigned u; float f; } v;
    v.u = ((unsigned)h) << 16;
    return v.f;
}
__device__ inline float fbs(short h) { return fb((unsigned short)h); }
__device__ inline f32x4 MF(short8 a, short8 b, f32x4 c) {
    return __builtin_amdgcn_mfma_f32_16x16x32_bf16(a, b, c, 0, 0, 0);
}
__device__ inline i32x4 MFI(i32x4 a, i32x4 b, i32x4 c) {
    return __builtin_amdgcn_mfma_i32_16x16x64_i8(a, b, c, 0, 0, 0);
}
__device__ inline unsigned pk4(float x, float y, float z, float w, float qs) {
    int a = (int)rintf(x * qs), b = (int)rintf(y * qs);
    int c = (int)rintf(z * qs), d = (int)rintf(w * qs);
    return (unsigned)(a & 255) | ((unsigned)(b & 255) << 8) |
           ((unsigned)(c & 255) << 16) | ((unsigned)(d & 255) << 24);
}

// raw barrier: LDS-visibility only, does NOT drain vmcnt
#define RAWBAR() do {                                            \
    __builtin_amdgcn_sched_barrier(0);                           \
    asm volatile("s_waitcnt lgkmcnt(0)" ::: "memory");           \
    __builtin_amdgcn_s_barrier();                                \
    __builtin_amdgcn_sched_barrier(0);                           \
} while (0)

// ---------------------------------------------------------------------------
// prep:
//  bid<128 : per-wave g: i8-quantize guid row (per-row max scale) ->
//            Bp1q[k/16][g] (16B); rg2q[g] = 2*(mx/127)/max(||g||,1e-8)
//  bid>=128: gg = bid-128: Bp2[gg][d][j] = bf16(guid[gg*8+j][d])
// ---------------------------------------------------------------------------
__global__ __launch_bounds__(256) void prep_kernel(const float* __restrict__ guid,
                                                   float* __restrict__ rg2q,
                                                   i32x4* __restrict__ Bp1q,
                                                   short8* __restrict__ Bp2) {
    int bid = blockIdx.x, tid = threadIdx.x;
    if (bid < 128) {
        int wave = tid >> 6, lane = tid & 63;
        int g = bid * 4 + wave;
        const float4* g4 = (const float4*)(guid + (size_t)g * D_);
        float4 v[4]; float ss = 0.f, mx = 0.f;
#pragma unroll
        for (int c = 0; c < 4; ++c) {          // lane owns k in [16*lane, 16*lane+16)
            float4 t = g4[lane * 4 + c]; v[c] = t;
            ss += t.x * t.x + t.y * t.y + t.z * t.z + t.w * t.w;
            mx = fmaxf(mx, fmaxf(fmaxf(fabsf(t.x), fabsf(t.y)),
                                 fmaxf(fabsf(t.z), fabsf(t.w))));
        }
#pragma unroll
        for (int m = 32; m >= 1; m >>= 1) {
            ss += __shfl_xor(ss, m, 64);
            mx = fmaxf(mx, __shfl_xor(mx, m, 64));
        }
        if (lane == 0) rg2q[g] = 2.f * (mx / 127.f) / fmaxf(sqrtf(ss), 1e-8f);
        float qs = 127.f / fmaxf(mx, 1e-20f);
        i32x4 o;
#pragma unroll
        for (int c = 0; c < 4; ++c) o[c] = (int)pk4(v[c].x, v[c].y, v[c].z, v[c].w, qs);
        Bp1q[(size_t)lane * G_ + g] = o;
    } else {
        int gg = bid - 128;
#pragma unroll
        for (int dd = 0; dd < 4; ++dd) {
            int d = tid + 256 * dd;
            short8 v;
#pragma unroll
            for (int j = 0; j < 8; ++j) v[j] = to_bf16(guid[(size_t)(gg * 8 + j) * D_ + d]);
            Bp2[(size_t)gg * D_ + d] = v;
        }
    }
}

// one i8 gemm1 K-step (K=64) for step ksv using B-ring entry q (3 m-tiles)
#define G1S(ksv, q)  {                                                            \
    const char* abp = D8 + (ksv) * 64 + quad * 16;                                \
    i32x4 a0 = *(const i32x4*)(abp + (size_t)l15 * D8ST);                         \
    i32x4 a1 = *(const i32x4*)(abp + (size_t)(16 + l15) * D8ST);                  \
    i32x4 a2 = *(const i32x4*)(abp + (size_t)(32 + l15) * D8ST);                  \
    acc1[0][0] = MFI(a0, q[0], acc1[0][0]); acc1[0][1] = MFI(a0, q[1], acc1[0][1]); \
    acc1[1][0] = MFI(a1, q[0], acc1[1][0]); acc1[1][1] = MFI(a1, q[1], acc1[1][1]); \
    acc1[2][0] = MFI(a2, q[0], acc1[2][0]); acc1[2][1] = MFI(a2, q[1], acc1[2][1]); }

// ---------------------------------------------------------------------------
// fused_kernel: round-11 verified skeleton (cvS V-build, 7 barriers, XCD
// swizzle, two-half gemm2) with gemm1 switched to i8 (halves the L2-bound
// Bp1 stream + gemm1 MFMA count; numerics validated rounds 5-8).
// NOTE: V-build MUST use the cvS-in-LDS variant; the per-wave sums[9]
// register variant crosses the 64-VGPR cliff and spills ~400 B/thread
// (rounds 5-8, 10: +104 MB WRITE, +29 us).
// ---------------------------------------------------------------------------
__global__ __launch_bounds__(1024, 4) void fused_kernel(const float* __restrict__ emb,
                                                        const i32x4* __restrict__ Bp1q,
                                                        const short8* __restrict__ Bp2,
                                                        const float* __restrict__ rg2q,
                                                        float* __restrict__ out) {
    __shared__ __align__(16) char RA[80512];   // bf16 diffs -> W -> IP
    __shared__ __align__(16) char RB[49920];   // i8 diffs -> V
    __shared__ float rg2s[G_];
    __shared__ float pred[NR][16];
    __shared__ float magS[NR], rmagS[NR], rmvqS[NR], mrS[NR], cvS[NR];
    __shared__ float rwsS[MTO];

    short* DH = (short*)RA;
    short* WD = (short*)RA;
    short* IP = (short*)RA;
    char*  D8 = RB;
    short* V  = (short*)RB;

    const int tid = threadIdx.x;
    const int wave = tid >> 6, lane = tid & 63;
    const int l15 = lane & 15, quad = lane >> 4;
    // XCD-contiguous swizzle: grid 256 = 8 XCDs x 32 (verified: FETCH 31->27 MB)
    const int bid0 = blockIdx.x;
    const int bid = ((bid0 & 7) << 5) | (bid0 >> 3);   // bijective on [0,256)
    const int b = bid >> 6;
    const int s0 = (bid & 63) << 5;
    const bool edge = (s0 == 0);

    if (tid < G_) rg2s[tid] = rg2q[tid];

    // ---- Phase 1: diffs. wave handles rows {w, 16+w, 32+w}; row rr -> t = s0-8+rr ----
#pragma unroll
    for (int ii = 0; ii < 3; ++ii) {
        int rr = wave + 16 * ii;
        int t = s0 - 8 + rr;
        bool valid = (t >= 0) && (rr < 39);
        float ss = 0.f, mx = 0.f;
        float4 dv[4];
        if (valid) {
            const float4* p = (const float4*)(emb + ((size_t)b * S_ + t) * D_);
#pragma unroll
            for (int j = 0; j < 4; ++j) {
                float4 x0 = p[lane + 64 * j];
                float4 x1 = p[lane + 64 * j + 256];
                float4 d = make_float4(x1.x - x0.x, x1.y - x0.y, x1.z - x0.z, x1.w - x0.w);
                dv[j] = d;
                ss += d.x * d.x + d.y * d.y + d.z * d.z + d.w * d.w;
                mx = fmaxf(mx, fmaxf(fmaxf(fabsf(d.x), fabsf(d.y)),
                                     fmaxf(fabsf(d.z), fabsf(d.w))));
            }
        } else {
#pragma unroll
            for (int j = 0; j < 4; ++j) dv[j] = make_float4(0.f, 0.f, 0.f, 0.f);
        }
#pragma unroll
        for (int m = 32; m >= 1; m >>= 1) {
            ss += __shfl_xor(ss, m, 64);
            mx = fmaxf(mx, __shfl_xor(mx, m, 64));
        }
        float mag = sqrtf(ss);
        if (lane == 0) {
            float rmag = (mag > 1e-6f) ? (1.0f / mag) : 0.0f;
            magS[rr]  = tanhf(2.0f * mag);                 // 0 for invalid
            rmagS[rr] = rmag;
            rmvqS[rr] = rmag * (mx / 127.f);               // i8 dot descale
        }
        float qs = 127.f / fmaxf(mx, 1e-20f);
#pragma unroll
        for (int j = 0; j < 4; ++j) {
            if (rr < 39) {
                s16x4 h;
                h[0] = to_bf16(dv[j].x); h[1] = to_bf16(dv[j].y);
                h[2] = to_bf16(dv[j].z); h[3] = to_bf16(dv[j].w);
                *(s16x4*)&DH[(size_t)rr * DHST + 4 * lane + 256 * j] = h;
            }
            *(unsigned*)&D8[(size_t)rr * D8ST + 4 * lane + 256 * j] =
                valid ? pk4(dv[j].x, dv[j].y, dv[j].z, dv[j].w, qs) : 0u;
        }
    }
    RAWBAR();                                            // bar1

    // helpers needing only magS/rmagS
    if (tid < NR) mrS[tid] = 0.6f * magS[tid] * rmagS[tid];
    if (tid < MTO) {
        int w = edge ? ((tid < 8) ? tid : 8) : 8;
        float rw = (w > 1) ? 0.9f / (float)(w - 1) : 0.f;
        float s = 0.f;
#pragma unroll
        for (int a = 1; a <= 8; ++a) {
            float lin = (a <= w) ? ((w > 1) ? (0.1f + rw * (float)(w - a)) : 0.1f) : 0.f;
            s += lin * magS[tid + 8 - a];
        }
        rwsS[tid] = 1.0f / fmaxf(s, 1e-8f);
    }

    // ---- Phase 2: i8 gemm1 [48 x 512], K=1024 (16 steps of 64), 4-deep ring.
    //      Ring registers die before the FIR. ----
    i32x4 acc1[3][2];
#pragma unroll
    for (int mt = 0; mt < 3; ++mt)
#pragma unroll
        for (int nt = 0; nt < 2; ++nt) acc1[mt][nt] = (i32x4)0;
    {
        const i32x4* PB = Bp1q + (size_t)quad * G_ + wave * 32 + l15;
        i32x4 q0[2], q1[2], q2[2], q3[2];
        q0[0] = PB[0];        q0[1] = PB[16];
        q1[0] = PB[2048];     q1[1] = PB[2048 + 16];
        q2[0] = PB[4096];     q2[1] = PB[4096 + 16];
        q3[0] = PB[6144];     q3[1] = PB[6144 + 16];
#pragma unroll
        for (int k4 = 0; k4 < 16; k4 += 4) {
            G1S(k4 + 0, q0); if (k4 < 12) { q0[0] = PB[(size_t)(k4 + 4) * 2048]; q0[1] = PB[(size_t)(k4 + 4) * 2048 + 16]; }
            G1S(k4 + 1, q1); if (k4 < 12) { q1[0] = PB[(size_t)(k4 + 5) * 2048]; q1[1] = PB[(size_t)(k4 + 5) * 2048 + 16]; }
            G1S(k4 + 2, q2); if (k4 < 12) { q2[0] = PB[(size_t)(k4 + 6) * 2048]; q2[1] = PB[(size_t)(k4 + 6) * 2048 + 16]; }
            G1S(k4 + 3, q3); if (k4 < 12) { q3[0] = PB[(size_t)(k4 + 7) * 2048]; q3[1] = PB[(size_t)(k4 + 7) * 2048 + 16]; }
        }
    }
    RAWBAR();                                            // mrS/rwsS visible

    // ---- Phase 3: normed-part 8-tap FIR over bf16 diffs. lane owns column d = tid ----
    float np_[MTO];
    {
        float pr[8];
#pragma unroll
        for (int r = 0; r < 8; ++r) pr[r] = mrS[r] * fbs(DH[(size_t)r * DHST + tid]);
        if (!edge) {
#pragma unroll
            for (int i = 0; i < MTO; ++i) {
                float s = 0.f;
#pragma unroll
                for (int a = 1; a <= 8; ++a)
                    s += (0.1f + (0.9f / 7.f) * (float)(8 - a)) * pr[(i + 8 - a) & 7];
                np_[i] = s;
                if (i < 31) pr[i & 7] = mrS[i + 8] * fbs(DH[(size_t)(i + 8) * DHST + tid]);
            }
        } else {
#pragma unroll
            for (int i = 0; i < MTO; ++i) {
                int w = (i < 8) ? i : 8;
                float rw = (w > 1) ? 0.9f / (float)(w - 1) : 0.f;
                float s = 0.f;
#pragma unroll
                for (int a = 1; a <= 8; ++a) {
                    float lin = (a <= w) ? ((w > 1) ? (0.1f + rw * (float)(w - a)) : 0.1f) : 0.f;
                    s += lin * pr[(i + 8 - a) & 7];
                }
                np_[i] = s;
                if (i < 31) pr[i & 7] = mrS[i + 8] * fbs(DH[(size_t)(i + 8) * DHST + tid]);
            }
        }
    }

    // ---- Phase 4: softmax (no max-sub; logits in [-2,2]); exp stored back
    //      into acc1's registers as float bits ----
    float psum[3][4];
#pragma unroll
    for (int mt = 0; mt < 3; ++mt)
#pragma unroll
        for (int r2 = 0; r2 < 4; ++r2) psum[mt][r2] = 0.f;
    {
        float rmv[3][4];
#pragma unroll
        for (int mt = 0; mt < 3; ++mt)
#pragma unroll
            for (int r2 = 0; r2 < 4; ++r2) rmv[mt][r2] = rmvqS[mt * 16 + quad * 4 + r2];
#pragma unroll
        for (int mt = 0; mt < 3; ++mt)
#pragma unroll
            for (int nt = 0; nt < 2; ++nt) {
                float rgv = rg2s[wave * 32 + nt * 16 + l15];
#pragma unroll
                for (int r2 = 0; r2 < 4; ++r2) {
                    float e = __expf((float)acc1[mt][nt][r2] * rgv * rmv[mt][r2]);
                    acc1[mt][nt][r2] = __float_as_int(e);
                    psum[mt][r2] += e;
                }
            }
#pragma unroll
        for (int m = 8; m >= 1; m >>= 1)
#pragma unroll
            for (int mt = 0; mt < 3; ++mt)
#pragma unroll
                for (int r2 = 0; r2 < 4; ++r2)
                    psum[mt][r2] += __shfl_xor(psum[mt][r2], m, 16);
    }
    RAWBAR();                    // bar2: all FIR/gemm1 reads done -> safe to overwrite RA/RB

    // W (exp) -> WD; partial sums -> pred
#pragma unroll
    for (int mt = 0; mt < 3; ++mt)
#pragma unroll
        for (int nt = 0; nt < 2; ++nt)
#pragma unroll
            for (int r2 = 0; r2 < 4; ++r2)
                WD[(size_t)(mt * 16 + quad * 4 + r2) * WST + wave * 32 + nt * 16 + l15] =
                    to_bf16(__int_as_float(acc1[mt][nt][r2]));
    if (l15 == 0) {
#pragma unroll
        for (int mt = 0; mt < 3; ++mt)
#pragma unroll
            for (int r2 = 0; r2 < 4; ++r2)
                pred[mt * 16 + quad * 4 + r2][wave] = psum[mt][r2];
    }
    RAWBAR();                    // bar3: W + pred visible
    if (tid < NR) {
        float s = 0.f;
#pragma unroll
        for (int w2 = 0; w2 < 16; ++w2) s += pred[tid][w2];
        cvS[tid] = 0.4f * magS[tid] / s;     // folds magw, 0.4, 1/sumexp
    }
    RAWBAR();                    // bar4: cvS visible

    // ---- Phase 5: V-build: V[i][g] = sum_a lin*cvS[i+8-a] * W[i+8-a][g]. wave: i=2w,2w+1 ----
#pragma unroll
    for (int ii = 0; ii < 2; ++ii) {
        int i = wave * 2 + ii;
        int w = edge ? ((i < 8) ? i : 8) : 8;
        float rw = (w > 1) ? 0.9f / (float)(w - 1) : 0.f;
        float c[8];
#pragma unroll
        for (int a = 1; a <= 8; ++a) {
            float lin = (a <= w) ? ((w > 1) ? (0.1f + rw * (float)(w - a)) : 0.1f) : 0.f;
            c[a - 1] = lin * cvS[i + 8 - a];
        }
        float v[8];
#pragma unroll
        for (int j = 0; j < 8; ++j) v[j] = 0.f;
#pragma unroll
        for (int a = 1; a <= 8; ++a) {
            short8 e = *(const short8*)&WD[(size_t)(i + 8 - a) * WST + lane * 8];
#pragma unroll
            for (int j = 0; j < 8; ++j) v[j] += c[a - 1] * fbs(e[j]);
        }
        short8 vo;
#pragma unroll
        for (int j = 0; j < 8; ++j) vo[j] = to_bf16(v[j]);
        *(short8*)&V[(size_t)i * VST + lane * 8] = vo;
    }
    RAWBAR();                    // bar5: V visible

    // ---- Phase 6: bf16 gemm2 [32 x 1024], K=512, two 32-d halves; IP -> RA ----
#pragma unroll
    for (int half = 0; half < 2; ++half) {
        f32x4 acc2[2][2];
#pragma unroll
        for (int mt = 0; mt < 2; ++mt)
#pragma unroll
            for (int nt = 0; nt < 2; ++nt) acc2[mt][nt] = (f32x4)0.f;
        const short8* Bb2 = Bp2 + (size_t)quad * D_ + wave * 64 + half * 32 + l15;
        short8 bc0 = Bb2[0], bc1 = Bb2[16], bn0, bn1;
#pragma unroll
        for (int ks = 0; ks < 16; ++ks) {
            if (ks < 15) {
                const short8* Bx = Bb2 + (size_t)(ks + 1) * 4 * D_;
                bn0 = Bx[0]; bn1 = Bx[16];
            }
            short8 a0 = *(const short8*)&V[(size_t)l15 * VST + ks * 32 + quad * 8];
            short8 a1 = *(const short8*)&V[(size_t)(16 + l15) * VST + ks * 32 + quad * 8];
            acc2[0][0] = MF(a0, bc0, acc2[0][0]); acc2[0][1] = MF(a0, bc1, acc2[0][1]);
            acc2[1][0] = MF(a1, bc0, acc2[1][0]); acc2[1][1] = MF(a1, bc1, acc2[1][1]);
            bc0 = bn0; bc1 = bn1;
        }
#pragma unroll
        for (int mt = 0; mt < 2; ++mt)
#pragma unroll
            for (int ntl = 0; ntl < 2; ++ntl) {
                int d2 = wave * 64 + half * 32 + ntl * 16 + l15;
#pragma unroll
                for (int r2 = 0; r2 < 4; ++r2)
                    IP[(size_t)(mt * 16 + quad * 4 + r2) * IPST + d2] =
                        to_bf16(acc2[mt][ntl][r2]);
            }
    }
    RAWBAR();                    // bar6: IP visible

    // ---- Phase 7: out = (NP + IP) * rws. lane owns column d = tid ----
    {
        float* ob = out + ((size_t)b * S_ + s0) * D_ + tid;
#pragma unroll
        for (int i = 0; i < MTO; ++i) {
            float ip = fbs(IP[(size_t)i * IPST + tid]);
            ob[(size_t)i * D_] = (np_[i] + ip) * rwsS[i];
        }
    }
}

// ---------------------------------------------------------------------------
extern "C" void kernel_launch(void* const* d_in, const int* in_sizes, int n_in,
                              void* d_out, int out_size, void* d_ws, size_t ws_size,
                              hipStream_t stream) {
    const float* emb  = (const float*)d_in[0];
    const float* guid = (const float*)d_in[1];
    float* out = (float*)d_out;
    char* ws = (char*)d_ws;

    float* rg2q = (float*)(ws + WSOFF_RG2);
    i32x4* Bp1q = (i32x4*)(ws + WSOFF_BP1);
    short8* Bp2 = (short8*)(ws + WSOFF_BP2);

    prep_kernel<<<192, 256, 0, stream>>>(guid, rg2q, Bp1q, Bp2);
    fused_kernel<<<256, 1024, 0, stream>>>(emb, Bp1q, Bp2, rg2q, out);
}